// Round 13
// baseline (583.439 us; speedup 1.0000x reference)
//
#include <hip/hip_runtime.h>
#include <hip/hip_bf16.h>

#define NPTS 2048
#define NB 4
#define KNN 32
#define NIN 33

static __device__ __forceinline__ float b2f(__hip_bfloat16 v) { return __bfloat162float(v); }
#define ISQ 0.99999499996875f /* 1/sqrt(1+1e-5) */

typedef __attribute__((ext_vector_type(8))) short short8v;   // 8 bf16 (4 VGPRs)
typedef __attribute__((ext_vector_type(4))) float f32x4;

// monotone order-preserving key for fp32 (no NaNs): a<b  <=>  ordkey(a)<ordkey(b)
static __device__ __forceinline__ unsigned ordkey(float f) {
  unsigned u = __float_as_uint(f);
  return u ^ (unsigned)(((int)u >> 31) | 0x80000000);
}

static __device__ __forceinline__ void loadv(const float* p, float (&d)[1]) { d[0] = *p; }
static __device__ __forceinline__ void loadv(const float* p, float (&d)[2]) {
  float2 v = *(const float2*)p; d[0] = v.x; d[1] = v.y;
}
static __device__ __forceinline__ void loadv(const float* p, float (&d)[4]) {
  float4 v = *(const float4*)p; d[0] = v.x; d[1] = v.y; d[2] = v.z; d[3] = v.w;
}

static __device__ __forceinline__ float wave_red_sum(float s) {
#pragma unroll
  for (int off = 32; off > 0; off >>= 1) s += __shfl_xor(s, off);
  return s;
}

// ---- dtype detect: flag=1 if buffer is bf16, 0 if fp32 ----
__global__ __launch_bounds__(64) void detect_kernel(const unsigned short* __restrict__ x,
                                                    int* __restrict__ flag) {
  int cnt = 0;
  for (int i = threadIdx.x; i < 512; i += 64) {
    unsigned e = (x[i] >> 7) & 0xFFu;
    if (e >= 0xC6u) cnt++;
  }
#pragma unroll
  for (int off = 32; off > 0; off >>= 1) cnt += __shfl_down(cnt, off);
  if (threadIdx.x == 0) flag[0] = (cnt == 0) ? 1 : 0;
}

struct CvtArgs {
  const void* src[NIN];
  int off[NIN + 1];
};

// blocks [0, nb1): convert all inputs into fp32 pool.
// blocks [nb1, ...): convert W5 (d_in[15]) directly to bf16 (1024*512 elems).
__global__ __launch_bounds__(256) void cvt_all_kernel(CvtArgs a, float* __restrict__ out,
                                                      int total, int nb1,
                                                      __hip_bfloat16* __restrict__ w5bf,
                                                      const int* __restrict__ flag) {
  if ((int)blockIdx.x < nb1) {
    int t = blockIdx.x * 256 + threadIdx.x;
    if (t >= total) return;
    int s = 0;
    while (t >= a.off[s + 1]) s++;
    int j = t - a.off[s];
    float v;
    if (flag[0]) v = b2f(((const __hip_bfloat16*)a.src[s])[j]);
    else         v = ((const float*)a.src[s])[j];
    out[t] = v;
  } else {
    int t = (blockIdx.x - nb1) * 256 + threadIdx.x;   // 1024*512
    if (flag[0]) w5bf[t] = ((const __hip_bfloat16*)a.src[15])[t];
    else         w5bf[t] = __float2bfloat16(((const float*)a.src[15])[t]);
  }
}

// xx[b,m] = sum_c x[b,c,m]^2  (layer-1 raw input only)
template <int C>
__global__ __launch_bounds__(256) void xx_kernel(const float* __restrict__ x, long bstride,
                                                 float* __restrict__ xx) {
  int t = blockIdx.x * 256 + threadIdx.x;
  int b = t / NPTS, m = t % NPTS;
  const float* xb = x + (long)b * bstride + m;
  float s = 0.f;
#pragma unroll
  for (int c = 0; c < C; ++c) { float v = xb[(long)c * NPTS]; s = fmaf(v, v, s); }
  xx[t] = s;
}

// symmetric pd-GEMM v2: 128x128 tile, 8x8 micro, parity-split LDS (2-way banks only),
// register-transposed mirror writes (no Ts buffer). Triangular grid over 16x16 tiles.
// perm(u) = (u<4) ? 2u : 2(u-4)+1  maps register index -> tile-local row/col.
template <int C>
__global__ __launch_bounds__(256) void pdgemmsym_kernel(const float* __restrict__ x, long bstride,
                                                        const float* __restrict__ xx,
                                                        unsigned* __restrict__ keys) {
  constexpr int KT = (C < 16) ? C : 16;
  __shared__ __align__(16) float At[KT][128];
  __shared__ __align__(16) float Bt[KT][128];
  int t = blockIdx.x;
  int tj = (int)((sqrtf(8.f * (float)t + 1.f) - 1.f) * 0.5f);
  while ((tj + 1) * (tj + 2) / 2 <= t) tj++;
  while (tj * (tj + 1) / 2 > t) tj--;
  int ti = t - tj * (tj + 1) / 2;            // ti <= tj
  int n0 = ti * 128, m0 = tj * 128;
  int tid = threadIdx.x, tx = tid & 15, ty = tid >> 4;
  const float* xb = x + (long)blockIdx.y * bstride;
  float acc[8][8] = {};
  for (int k0 = 0; k0 < C; k0 += KT) {
    for (int lin = tid; lin < KT * 128; lin += 256) {
      int r = lin >> 7, col = lin & 127;
      int cm = ((col & 1) << 6) + (col >> 1);
      At[r][cm] = xb[(long)(k0 + r) * NPTS + n0 + col];
      Bt[r][cm] = xb[(long)(k0 + r) * NPTS + m0 + col];
    }
    __syncthreads();
#pragma unroll
    for (int kc = 0; kc < KT; ++kc) {
      float4 ae = *(const float4*)&At[kc][ty * 4];
      float4 ao = *(const float4*)&At[kc][64 + ty * 4];
      float4 be = *(const float4*)&Bt[kc][tx * 4];
      float4 bo = *(const float4*)&Bt[kc][64 + tx * 4];
      float av[8] = {ae.x, ae.y, ae.z, ae.w, ao.x, ao.y, ao.z, ao.w};
      float bv[8] = {be.x, be.y, be.z, be.w, bo.x, bo.y, bo.z, bo.w};
#pragma unroll
      for (int ii = 0; ii < 8; ++ii)
#pragma unroll
        for (int jj = 0; jj < 8; ++jj)
          acc[ii][jj] = fmaf(av[ii], bv[jj], acc[ii][jj]);
    }
    __syncthreads();
  }
  const float* xxq = xx + (long)blockIdx.y * NPTS;
  float xxn[8], xxm[8];
#pragma unroll
  for (int u = 0; u < 8; ++u) {
    int pu = (u < 4) ? 2 * u : 2 * (u - 4) + 1;
    xxn[u] = xxq[n0 + ty * 8 + pu];
    xxm[u] = xxq[m0 + tx * 8 + pu];
  }
  // ordkeys in place (bit-stored in acc)
#pragma unroll
  for (int ii = 0; ii < 8; ++ii)
#pragma unroll
    for (int jj = 0; jj < 8; ++jj) {
      float pdv = (-xxn[ii] - (-2.f * acc[ii][jj])) - xxm[jj];
      acc[ii][jj] = __uint_as_float(ordkey(pdv));
    }
  unsigned* kb = keys + ((long)blockIdx.y << 22);
  // direct tile: row = n0+ty*8+perm(ii); cols m0+tx*8+c, register jj(c)
#pragma unroll
  for (int ii = 0; ii < 8; ++ii) {
    int pii = (ii < 4) ? 2 * ii : 2 * (ii - 4) + 1;
    long rbase = (long)(n0 + ty * 8 + pii) * NPTS + m0 + tx * 8;
    uint4 w0, w1;
    w0.x = __float_as_uint(acc[ii][0]); w0.y = __float_as_uint(acc[ii][4]);
    w0.z = __float_as_uint(acc[ii][1]); w0.w = __float_as_uint(acc[ii][5]);
    w1.x = __float_as_uint(acc[ii][2]); w1.y = __float_as_uint(acc[ii][6]);
    w1.z = __float_as_uint(acc[ii][3]); w1.w = __float_as_uint(acc[ii][7]);
    *(uint4*)&kb[rbase] = w0;
    *(uint4*)&kb[rbase + 4] = w1;
  }
  if (ti != tj) {
#pragma unroll
    for (int jj = 0; jj < 8; ++jj) {
      int pjj = (jj < 4) ? 2 * jj : 2 * (jj - 4) + 1;
      long rbase = (long)(m0 + tx * 8 + pjj) * NPTS + n0 + ty * 8;
      uint4 w0, w1;
      w0.x = __float_as_uint(acc[0][jj]); w0.y = __float_as_uint(acc[4][jj]);
      w0.z = __float_as_uint(acc[1][jj]); w0.w = __float_as_uint(acc[5][jj]);
      w1.x = __float_as_uint(acc[2][jj]); w1.y = __float_as_uint(acc[6][jj]);
      w1.z = __float_as_uint(acc[3][jj]); w1.w = __float_as_uint(acc[7][jj]);
      *(uint4*)&kb[rbase] = w0;
      *(uint4*)&kb[rbase + 4] = w1;
    }
  }
}

// top-32 SET select: per-lane top-4 candidates + ballot-counted radix + verify
__global__ __launch_bounds__(256) void select_kernel(const unsigned* __restrict__ keys,
                                                     int* __restrict__ idxout) {
  int wave = threadIdx.x >> 6, lane = threadIdx.x & 63;
  int q = blockIdx.x * 4 + wave;
  int bloc = q >> 11, n = q & 2047;
  const uint4* rp = (const uint4*)(keys + ((long)((bloc << 11) | n) << 11));
  unsigned K[32];
#pragma unroll
  for (int t = 0; t < 8; ++t) {
    uint4 kk = rp[t * 64 + lane];
    K[4 * t + 0] = kk.x; K[4 * t + 1] = kk.y; K[4 * t + 2] = kk.z; K[4 * t + 3] = kk.w;
  }
  unsigned t0 = 0, t1 = 0, t2 = 0, t3 = 0;
#pragma unroll
  for (int s = 0; s < 32; ++s) {
    unsigned k = K[s];
    if (k > t3) {
      if (k > t1) {
        if (k > t0) { t3 = t2; t2 = t1; t1 = t0; t0 = k; }
        else        { t3 = t2; t2 = t1; t1 = k; }
      } else {
        if (k > t2) { t3 = t2; t2 = k; }
        else        { t3 = k; }
      }
    }
  }
  unsigned orv = t0 | t1 | t2 | t3, andv = t0 & t1 & t2 & t3;
#pragma unroll
  for (int xm = 32; xm >= 1; xm >>= 1) {
    orv  |= __shfl_xor(orv, xm);
    andv &= __shfl_xor(andv, xm);
  }
  unsigned V = orv ^ andv;
  unsigned P = andv & ~V;
  int need = KNN;
  for (int b = 31; b >= 0; --b) {
    unsigned bit = 1u << b;
    if (!(V & bit)) continue;
    unsigned hm = 0xFFFFFFFFu << b;
    unsigned Pb = (P & hm) | bit;
    int c = (int)__popcll(__ballot((t0 & hm) == Pb)) +
            (int)__popcll(__ballot((t1 & hm) == Pb)) +
            (int)__popcll(__ballot((t2 & hm) == Pb)) +
            (int)__popcll(__ballot((t3 & hm) == Pb));
    if (c >= need) P |= bit;
    else need -= c;
  }
  int cg = 0;
#pragma unroll
  for (int s = 0; s < 32; ++s) cg += (int)__popcll(__ballot(K[s] > P));
  if (cg > KNN - 1) {
    unsigned orf = K[0], anf = K[0];
#pragma unroll
    for (int s = 1; s < 32; ++s) { orf |= K[s]; anf &= K[s]; }
#pragma unroll
    for (int xm = 32; xm >= 1; xm >>= 1) {
      orf |= __shfl_xor(orf, xm);
      anf &= __shfl_xor(anf, xm);
    }
    unsigned Vf = orf ^ anf;
    P = anf & ~Vf;
    need = KNN;
    for (int b = 31; b >= 0; --b) {
      unsigned bit = 1u << b;
      if (!(Vf & bit)) continue;
      unsigned hm = 0xFFFFFFFFu << b;
      unsigned Pb = (P & hm) | bit;
      int c = 0;
#pragma unroll
      for (int s = 0; s < 32; ++s) c += (int)__popcll(__ballot((K[s] & hm) == Pb));
      if (c >= need) P |= bit;
      else need -= c;
    }
  }
  int* orow = idxout + ((bloc << 11) | n) * KNN;
  int base = 0;
  unsigned eqmask = 0;
#pragma unroll
  for (int s = 0; s < 32; ++s) {
    bool take = K[s] > P;
    unsigned long long bal = __ballot(take);
    if (take) {
      int pos = base + (int)__popcll(bal & ((1ull << lane) - 1ull));
      orow[pos] = ((s >> 2) << 8) + lane * 4 + (s & 3);
    }
    base += (int)__popcll(bal);
    if (K[s] == P) eqmask |= (1u << s);
  }
  int rem = KNN - base;
  for (int it = 0; it < rem; ++it) {
    unsigned mym = 0xFFFFFFFFu;
    if (eqmask) {
      int s = __ffs(eqmask) - 1;
      mym = (unsigned)(((s >> 2) << 8) + lane * 4 + (s & 3));
    }
    unsigned wm = mym;
#pragma unroll
    for (int xm = 32; xm >= 1; xm >>= 1) {
      unsigned o = __shfl_xor(wm, xm);
      wm = o < wm ? o : wm;
    }
    if (mym == wm) {
      orow[base + it] = (int)wm;
      eqmask &= eqmask - 1;
    }
  }
}

// yzt: point-major GEMM.  yt[b][m][o], zt[b][m][o]
template <int C>
__global__ __launch_bounds__(256) void yzt_kernel(const float* __restrict__ x, long bstride,
                                                  const float* __restrict__ W, int O,
                                                  float* __restrict__ yt, float* __restrict__ zt) {
  constexpr int KT = (C < 16) ? C : 16;
  __shared__ __align__(16) float Xs[KT][64];
  __shared__ __align__(16) float Wy[KT][64];
  __shared__ __align__(16) float Wp[KT][64];
  int b = blockIdx.z, m0 = blockIdx.y * 64, o0 = blockIdx.x * 64;
  int tid = threadIdx.x, tx = tid & 15, ty = tid >> 4;
  const float* xb = x + (long)b * bstride;
  const int twoC = 2 * C;
  float accy[4][4] = {}, accp[4][4] = {};
  for (int k0 = 0; k0 < C; k0 += KT) {
    for (int lin = tid; lin < KT * 64; lin += 256) {
      int r = lin >> 6, col = lin & 63;
      Xs[r][col] = xb[(long)(k0 + r) * NPTS + m0 + col];
      float wy = W[(o0 + col) * twoC + k0 + r];
      Wy[r][col] = wy;
      Wp[r][col] = W[(o0 + col) * twoC + C + k0 + r] - wy;
    }
    __syncthreads();
#pragma unroll
    for (int kc = 0; kc < KT; ++kc) {
      float4 wv = *(const float4*)&Wy[kc][tx * 4];
      float4 pv = *(const float4*)&Wp[kc][tx * 4];
      float xm[4];
      xm[0] = Xs[kc][ty * 4 + 0]; xm[1] = Xs[kc][ty * 4 + 1];
      xm[2] = Xs[kc][ty * 4 + 2]; xm[3] = Xs[kc][ty * 4 + 3];
#pragma unroll
      for (int i = 0; i < 4; ++i) {
        accy[i][0] = fmaf(xm[i], wv.x, accy[i][0]);
        accy[i][1] = fmaf(xm[i], wv.y, accy[i][1]);
        accy[i][2] = fmaf(xm[i], wv.z, accy[i][2]);
        accy[i][3] = fmaf(xm[i], wv.w, accy[i][3]);
        accp[i][0] = fmaf(xm[i], pv.x, accp[i][0]);
        accp[i][1] = fmaf(xm[i], pv.y, accp[i][1]);
        accp[i][2] = fmaf(xm[i], pv.z, accp[i][2]);
        accp[i][3] = fmaf(xm[i], pv.w, accp[i][3]);
      }
    }
    __syncthreads();
  }
#pragma unroll
  for (int i = 0; i < 4; ++i) {
    long base = ((long)b * NPTS + m0 + ty * 4 + i) * O + o0 + tx * 4;
    *(float4*)&yt[base] = make_float4(accy[i][0], accy[i][1], accy[i][2], accy[i][3]);
    *(float4*)&zt[base] = make_float4(accp[i][0], accp[i][1], accp[i][2], accp[i][3]);
  }
}

// gmaxt: one wave per query n; emits xx for next layer + bf16 point-major cat copy
template <int RO>
__global__ __launch_bounds__(256) void gmaxt_kernel(const float* __restrict__ yt,
                                                    const float* __restrict__ zt,
                                                    const int* __restrict__ idx,
                                                    const float* __restrict__ g,
                                                    const float* __restrict__ bb,
                                                    float* __restrict__ out, long obstride,
                                                    float* __restrict__ xxout,
                                                    __hip_bfloat16* __restrict__ catbf, int loff) {
  constexpr int O = RO * 64;
  int wave = threadIdx.x >> 6, lane = threadIdx.x & 63;
  int n = blockIdx.x * 4 + wave, b = blockIdx.y;
  int jreg = idx[((b << 11) + n) * KNN + (lane & 31)];
  int obase = lane * RO;
  float gs[RO], bs[RO], zr[RO], acc[RO];
  loadv(zt + ((long)(b << 11) + n) * O + obase, zr);
#pragma unroll
  for (int r = 0; r < RO; ++r) {
    gs[r] = g[obase + r] * ISQ;
    bs[r] = bb[obase + r];
    acc[r] = -INFINITY;
  }
  const float* yb = yt + ((long)(b << 11)) * O + obase;
#pragma unroll
  for (int k = 0; k < KNN; ++k) {
    int j = __shfl(jreg, k);
    float yv[RO];
    loadv(yb + (long)j * O, yv);
#pragma unroll
    for (int r = 0; r < RO; ++r) {
      float v = fmaf(gs[r], yv[r] + zr[r], bs[r]);
      v = v >= 0.f ? v : 0.2f * v;
      acc[r] = fmaxf(acc[r], v);
    }
  }
  float* op = out + (long)b * obstride + (long)obase * NPTS + n;
#pragma unroll
  for (int r = 0; r < RO; ++r) op[(long)r * NPTS] = acc[r];
  __hip_bfloat16* cb = catbf + ((long)(b << 11) + n) * 512 + loff + obase;
#pragma unroll
  for (int r = 0; r < RO; ++r) cb[r] = __float2bfloat16(acc[r]);
  if (xxout) {
    float ss = 0.f;
#pragma unroll
    for (int r = 0; r < RO; ++r) ss = fmaf(acc[r], acc[r], ss);
    ss = wave_red_sum(ss);
    if (lane == 0) xxout[(b << 11) + n] = ss;
  }
}

// MFMA W5 GEMM + BN + leaky + 64n partial max. LDS-staged B, double-buffered.
__global__ __launch_bounds__(256) void gemm5m_kernel(const __hip_bfloat16* __restrict__ catbf,
                                                     const __hip_bfloat16* __restrict__ w5bf,
                                                     const float* __restrict__ g5,
                                                     const float* __restrict__ b5,
                                                     float* __restrict__ pmax) {
  __shared__ __align__(16) short Bs[2][8 * 64 * 8];
  int b = blockIdx.z, po0 = blockIdx.y * 128, n0 = blockIdx.x * 64;
  int wave = threadIdx.x >> 6, lane = threadIdx.x & 63;
  int quad = lane >> 4, l15 = lane & 15;
  const short* cbase = (const short*)catbf + ((long)(b << 11) + n0) * 512;
  const short* abase0 = (const short*)w5bf + (long)(po0 + wave * 32 + l15) * 512 + quad * 8;
  const short* abase1 = abase0 + 16 * 512;
  const short* bsrc0 = cbase + (long)lane * 512 + (2 * wave + 0) * 8;
  const short* bsrc1 = cbase + (long)lane * 512 + (2 * wave + 1) * 8;
  short* bdst0 = &Bs[0][((2 * wave + 0) * 64 + lane) * 8];
  short* bdst1 = &Bs[0][((2 * wave + 1) * 64 + lane) * 8];
  const int bufstride = 8 * 64 * 8;

  short8v Br[2][2], Ar[2][2][2];
  f32x4 acc[2][4] = {};

  Br[0][0] = *(const short8v*)(bsrc0);
  Br[0][1] = *(const short8v*)(bsrc1);
#pragma unroll
  for (int h = 0; h < 2; ++h)
#pragma unroll
    for (int j = 0; j < 2; ++j)
      Ar[0][h][j] = *(const short8v*)((h ? abase1 : abase0) + j * 32);
  *(short8v*)bdst0 = Br[0][0];
  *(short8v*)bdst1 = Br[0][1];
  Br[1][0] = *(const short8v*)(bsrc0 + 64);
  Br[1][1] = *(const short8v*)(bsrc1 + 64);
#pragma unroll
  for (int h = 0; h < 2; ++h)
#pragma unroll
    for (int j = 0; j < 2; ++j)
      Ar[1][h][j] = *(const short8v*)((h ? abase1 : abase0) + 64 + j * 32);
  __syncthreads();

  for (int it = 0; it < 8; ++it) {
    int cur = it & 1;
    const short* lb = &Bs[cur][0];
#pragma unroll
    for (int j = 0; j < 2; ++j) {
#pragma unroll
      for (int nt = 0; nt < 4; ++nt) {
        short8v bf = *(const short8v*)(lb + ((j * 4 + quad) * 64 + nt * 16 + l15) * 8);
        acc[0][nt] = __builtin_amdgcn_mfma_f32_16x16x32_bf16(Ar[cur][0][j], bf, acc[0][nt], 0, 0, 0);
        acc[1][nt] = __builtin_amdgcn_mfma_f32_16x16x32_bf16(Ar[cur][1][j], bf, acc[1][nt], 0, 0, 0);
      }
    }
    if (it < 7) {
      if (it < 6) {
        int ks = (it + 2) * 64;
        Br[cur][0] = *(const short8v*)(bsrc0 + ks);
        Br[cur][1] = *(const short8v*)(bsrc1 + ks);
#pragma unroll
        for (int h = 0; h < 2; ++h)
#pragma unroll
          for (int j = 0; j < 2; ++j)
            Ar[cur][h][j] = *(const short8v*)((h ? abase1 : abase0) + ks + j * 32);
      }
      int nb = cur ^ 1;
      *(short8v*)(bdst0 + nb * bufstride) = Br[nb][0];
      *(short8v*)(bdst1 + nb * bufstride) = Br[nb][1];
      __syncthreads();
    }
  }

#pragma unroll
  for (int h = 0; h < 2; ++h) {
#pragma unroll
    for (int r = 0; r < 4; ++r) {
      int po = po0 + wave * 32 + h * 16 + quad * 4 + r;
      float sc = g5[po] * ISQ;
      float bi = b5[po];
      float mx = -INFINITY;
#pragma unroll
      for (int nt = 0; nt < 4; ++nt) {
        float v = fmaf(sc, acc[h][nt][r], bi);
        v = v >= 0.f ? v : 0.2f * v;
        mx = fmaxf(mx, v);
      }
#pragma unroll
      for (int xm = 1; xm < 16; xm <<= 1) mx = fmaxf(mx, __shfl_xor(mx, xm));
      if (l15 == 0) pmax[(long)(b * 1024 + po) * 32 + blockIdx.x] = mx;
    }
  }
}

// merged: blocks 0..15 -> global-max reduce of pmax into v; blocks 16..17 -> lf/nf
__global__ __launch_bounds__(256) void redlfnf_kernel(const float* __restrict__ pmax,
                                                      const float* __restrict__ l,
                                                      const float* __restrict__ nn,
                                                      const float* __restrict__ W6,
                                                      const float* __restrict__ g6,
                                                      const float* __restrict__ b6,
                                                      const float* __restrict__ W7,
                                                      const float* __restrict__ g7,
                                                      const float* __restrict__ b7,
                                                      float* __restrict__ v) {
  if (blockIdx.x < 16) {
    int t = blockIdx.x * 256 + threadIdx.x;   // b*1024 + po  (4096)
    float mx = -INFINITY;
#pragma unroll
    for (int j = 0; j < 32; ++j) mx = fmaxf(mx, pmax[(long)t * 32 + j]);
    int b = t >> 10, po = t & 1023;
    v[b * 1152 + po] = mx;
  } else {
    int idx = (blockIdx.x - 16) * 256 + threadIdx.x;  // 512 work items
    int b = idx >> 7, t = idx & 127;
    if (t < 64) {
      float s = 0.f;
#pragma unroll
      for (int c = 0; c < 5; ++c) s = fmaf(W6[t * 5 + c], l[b * 5 + c], s);
      float val = fmaf(g6[t] * ISQ, s, b6[t]);
      v[b * 1152 + 1024 + t] = val >= 0.f ? val : 0.2f * val;
    } else {
      int o = t - 64;
      float s = 0.f;
#pragma unroll
      for (int c = 0; c < 7; ++c) s = fmaf(W7[o * 7 + c], nn[b * 7 + c], s);
      float val = fmaf(g7[o] * ISQ, s, b7[o]);
      v[b * 1152 + 1088 + o] = val >= 0.f ? val : 0.2f * val;
    }
  }
}

// one wave per output row; lane-strided dot + shuffle reduce
__global__ __launch_bounds__(256) void head1_kernel(const float* __restrict__ v,
                                                    const float* __restrict__ L1,
                                                    const float* __restrict__ g8,
                                                    const float* __restrict__ b8,
                                                    float* __restrict__ v1) {
  int wave = threadIdx.x >> 6, lane = threadIdx.x & 63;
  int t = blockIdx.x * 4 + wave;   // b*512 + o  (2048)
  int b = t >> 9, o = t & 511;
  const float* vb = v + b * 1152;
  const float* wr = L1 + (long)o * 1152;
  float s = 0.f;
#pragma unroll
  for (int c = lane; c < 1152; c += 64) s = fmaf(wr[c], vb[c], s);
  s = wave_red_sum(s);
  if (lane == 0) {
    float val = fmaf(g8[o] * ISQ, s, b8[o]);
    v1[t] = fmaxf(val, 0.f);
  }
}

__global__ __launch_bounds__(256) void head2_kernel(const float* __restrict__ v1,
                                                    const float* __restrict__ L2,
                                                    const float* __restrict__ L2b,
                                                    const float* __restrict__ g9,
                                                    const float* __restrict__ b9,
                                                    float* __restrict__ v2) {
  int wave = threadIdx.x >> 6, lane = threadIdx.x & 63;
  int t = blockIdx.x * 4 + wave;   // b*256 + o  (1024)
  int b = t >> 8, o = t & 255;
  const float* vb = v1 + b * 512;
  const float* wr = L2 + (long)o * 512;
  float s = 0.f;
#pragma unroll
  for (int c = lane; c < 512; c += 64) s = fmaf(wr[c], vb[c], s);
  s = wave_red_sum(s);
  if (lane == 0) {
    float sv = s + L2b[o];
    float val = fmaf(g9[o] * ISQ, sv, b9[o]);
    v2[t] = fmaxf(val, 0.f);
  }
}

__global__ __launch_bounds__(256) void head3_kernel(const float* __restrict__ v2,
                                                    const float* __restrict__ L3,
                                                    const float* __restrict__ L3b,
                                                    void* __restrict__ out,
                                                    const int* __restrict__ flag) {
  int wave = threadIdx.x >> 6, lane = threadIdx.x & 63;
  int t = blockIdx.x * 4 + wave;   // b*28 + o  (112)
  if (t >= 112) return;
  int b = t / 28, o = t % 28;
  const float* vb = v2 + b * 256;
  const float* wr = L3 + o * 256;
  float s = 0.f;
#pragma unroll
  for (int c = lane; c < 256; c += 64) s = fmaf(wr[c], vb[c], s);
  s = wave_red_sum(s);
  if (lane == 0) {
    float sv = s + L3b[o];
    if (flag[0]) ((__hip_bfloat16*)out)[t] = __float2bfloat16(sv);
    else         ((float*)out)[t] = sv;
  }
}

extern "C" void kernel_launch(void* const* d_in, const int* in_sizes, int n_in,
                              void* d_out, int out_size, void* d_ws, size_t ws_size,
                              hipStream_t stream) {
  CvtArgs ca;
  int off[NIN + 1];
  off[0] = 0;
  for (int i = 0; i < NIN; ++i) {
    ca.src[i] = d_in[i];
    off[i + 1] = off[i] + in_sizes[i];
    ca.off[i] = off[i];
  }
  ca.off[NIN] = off[NIN];
  const int total = off[NIN];

  int* flag = (int*)d_ws;
  float* fin = (float*)((char*)d_ws + 64);
  const float* xf  = fin + off[0];
  const float* lf  = fin + off[1];
  const float* nf  = fin + off[2];
  const float* W1f = fin + off[3];  const float* g1f = fin + off[4];  const float* b1f = fin + off[5];
  const float* W2f = fin + off[6];  const float* g2f = fin + off[7];  const float* b2f_ = fin + off[8];
  const float* W3f = fin + off[9];  const float* g3f = fin + off[10]; const float* b3f = fin + off[11];
  const float* W4f = fin + off[12]; const float* g4f = fin + off[13]; const float* b4f = fin + off[14];
  const float* g5f = fin + off[16]; const float* b5f = fin + off[17];
  const float* W6f = fin + off[18]; const float* g6f = fin + off[19]; const float* b6f = fin + off[20];
  const float* W7f = fin + off[21]; const float* g7f = fin + off[22]; const float* b7f = fin + off[23];
  const float* L1f = fin + off[24]; const float* g8f = fin + off[25]; const float* b8f = fin + off[26];
  const float* L2f = fin + off[27]; const float* L2bf = fin + off[28];
  const float* g9f = fin + off[29]; const float* b9f = fin + off[30];
  const float* L3f = fin + off[31]; const float* L3bf = fin + off[32];

  float* p = fin + ((total + 15) & ~15);
  float* cat  = p;                               // 4*512*2048 (fp32, channel-major)
  float* yb   = cat + 4 * 512 * NPTS;            // 4*2048*256 (point-major)
  float* zb   = yb + 4 * 256 * NPTS;             // 4*2048*256 (point-major)
  float* xxb  = zb + 4 * 256 * NPTS;             // 4*2048
  int*   idxb = (int*)(xxb + 4 * NPTS);          // 4*2048*32
  float* pmax = (float*)(idxb + 4 * NPTS * KNN); // 4*1024*32
  float* vb   = pmax + 4 * 1024 * 32;            // 4*1152
  float* v1b  = vb + 4 * 1152;                   // 4*512
  float* v2b  = v1b + 4 * 512;                   // 4*256
  __hip_bfloat16* w5bf  = (__hip_bfloat16*)(v2b + 4 * 256);           // 1024*512 bf16
  __hip_bfloat16* catbf = w5bf + 1024 * 512;                          // 4*2048*512 bf16
  unsigned* keys_tail = (unsigned*)(catbf + (size_t)4 * NPTS * 512);

  size_t need_full = (size_t)((char*)(keys_tail + (size_t)NB * NPTS * NPTS) - (char*)d_ws);
  int bpass = (ws_size >= need_full) ? NB : 1;
  unsigned* keys = (bpass == NB) ? keys_tail : (unsigned*)yb;

  const long bst1 = 3L * NPTS;
  const long bstc = 512L * NPTS;
  const int NTRI = 16 * 17 / 2;   // 136 triangular 128x128 tiles
  const int nb1 = (total + 255) / 256;

  detect_kernel<<<1, 64, 0, stream>>>((const unsigned short*)d_in[0], flag);
  cvt_all_kernel<<<nb1 + 2048, 256, 0, stream>>>(ca, fin, total, nb1, w5bf, flag);

  // ---- layer 1: C=3, O=64
  xx_kernel<3><<<32, 256, 0, stream>>>(xf, bst1, xxb);
  for (int b0 = 0; b0 < NB; b0 += bpass) {
    pdgemmsym_kernel<3><<<dim3(NTRI, bpass), 256, 0, stream>>>(xf + b0 * bst1, bst1, xxb + b0 * NPTS, keys);
    select_kernel<<<512 * bpass, 256, 0, stream>>>(keys, idxb + (long)b0 * NPTS * KNN);
  }
  yzt_kernel<3><<<dim3(1, 32, NB), 256, 0, stream>>>(xf, bst1, W1f, 64, yb, zb);
  gmaxt_kernel<1><<<dim3(512, NB), 256, 0, stream>>>(yb, zb, idxb, g1f, b1f, cat, bstc, xxb, catbf, 0);

  // ---- layer 2: C=64, O=64
  for (int b0 = 0; b0 < NB; b0 += bpass) {
    pdgemmsym_kernel<64><<<dim3(NTRI, bpass), 256, 0, stream>>>(cat + b0 * bstc, bstc, xxb + b0 * NPTS, keys);
    select_kernel<<<512 * bpass, 256, 0, stream>>>(keys, idxb + (long)b0 * NPTS * KNN);
  }
  yzt_kernel<64><<<dim3(1, 32, NB), 256, 0, stream>>>(cat, bstc, W2f, 64, yb, zb);
  gmaxt_kernel<1><<<dim3(512, NB), 256, 0, stream>>>(yb, zb, idxb, g2f, b2f_, cat + 64L * NPTS, bstc, xxb, catbf, 64);

  // ---- layer 3: C=64, O=128
  for (int b0 = 0; b0 < NB; b0 += bpass) {
    pdgemmsym_kernel<64><<<dim3(NTRI, bpass), 256, 0, stream>>>(cat + 64L * NPTS + b0 * bstc, bstc, xxb + b0 * NPTS, keys);
    select_kernel<<<512 * bpass, 256, 0, stream>>>(keys, idxb + (long)b0 * NPTS * KNN);
  }
  yzt_kernel<64><<<dim3(2, 32, NB), 256, 0, stream>>>(cat + 64L * NPTS, bstc, W3f, 128, yb, zb);
  gmaxt_kernel<2><<<dim3(512, NB), 256, 0, stream>>>(yb, zb, idxb, g3f, b3f, cat + 128L * NPTS, bstc, xxb, catbf, 128);

  // ---- layer 4: C=128, O=256
  for (int b0 = 0; b0 < NB; b0 += bpass) {
    pdgemmsym_kernel<128><<<dim3(NTRI, bpass), 256, 0, stream>>>(cat + 128L * NPTS + b0 * bstc, bstc, xxb + b0 * NPTS, keys);
    select_kernel<<<512 * bpass, 256, 0, stream>>>(keys, idxb + (long)b0 * NPTS * KNN);
  }
  yzt_kernel<128><<<dim3(4, 32, NB), 256, 0, stream>>>(cat + 128L * NPTS, bstc, W4f, 256, yb, zb);
  gmaxt_kernel<4><<<dim3(512, NB), 256, 0, stream>>>(yb, zb, idxb, g4f, b4f, cat + 256L * NPTS, bstc, (float*)nullptr, catbf, 256);

  // ---- conv5 (bf16 MFMA, LDS-staged B, double-buffered) + BN + leaky + global max
  gemm5m_kernel<<<dim3(32, 8, NB), 256, 0, stream>>>(catbf, w5bf, g5f, b5f, pmax);
  redlfnf_kernel<<<18, 256, 0, stream>>>(pmax, lf, nf, W6f, g6f, b6f, W7f, g7f, b7f, vb);

  head1_kernel<<<512, 256, 0, stream>>>(vb, L1f, g8f, b8f, v1b);
  head2_kernel<<<256, 256, 0, stream>>>(v1b, L2f, L2bf, g9f, b9f, v2b);
  head3_kernel<<<28, 256, 0, stream>>>(v2b, L3f, L3bf, d_out, flag);
}

// Round 14
// 529.990 us; speedup vs baseline: 1.1009x; 1.1009x over previous
//
#include <hip/hip_runtime.h>
#include <hip/hip_bf16.h>

#define NPTS 2048
#define NB 4
#define KNN 32
#define NIN 33

static __device__ __forceinline__ float b2f(__hip_bfloat16 v) { return __bfloat162float(v); }
#define ISQ 0.99999499996875f /* 1/sqrt(1+1e-5) */

typedef __attribute__((ext_vector_type(8))) short short8v;   // 8 bf16 (4 VGPRs)
typedef __attribute__((ext_vector_type(4))) float f32x4;

// monotone order-preserving key for fp32 (no NaNs): a<b  <=>  ordkey(a)<ordkey(b)
static __device__ __forceinline__ unsigned ordkey(float f) {
  unsigned u = __float_as_uint(f);
  return u ^ (unsigned)(((int)u >> 31) | 0x80000000);
}

static __device__ __forceinline__ void loadv(const float* p, float (&d)[1]) { d[0] = *p; }
static __device__ __forceinline__ void loadv(const float* p, float (&d)[2]) {
  float2 v = *(const float2*)p; d[0] = v.x; d[1] = v.y;
}
static __device__ __forceinline__ void loadv(const float* p, float (&d)[4]) {
  float4 v = *(const float4*)p; d[0] = v.x; d[1] = v.y; d[2] = v.z; d[3] = v.w;
}

static __device__ __forceinline__ float wave_red_sum(float s) {
#pragma unroll
  for (int off = 32; off > 0; off >>= 1) s += __shfl_xor(s, off);
  return s;
}

// ---- dtype detect: flag=1 if buffer is bf16, 0 if fp32 ----
__global__ __launch_bounds__(64) void detect_kernel(const unsigned short* __restrict__ x,
                                                    int* __restrict__ flag) {
  int cnt = 0;
  for (int i = threadIdx.x; i < 512; i += 64) {
    unsigned e = (x[i] >> 7) & 0xFFu;
    if (e >= 0xC6u) cnt++;
  }
#pragma unroll
  for (int off = 32; off > 0; off >>= 1) cnt += __shfl_down(cnt, off);
  if (threadIdx.x == 0) flag[0] = (cnt == 0) ? 1 : 0;
}

struct CvtArgs {
  const void* src[NIN];
  int off[NIN + 1];
};

// blocks [0, nb1): convert all inputs into fp32 pool.
// blocks [nb1, ...): convert W5 (d_in[15]) directly to bf16 (1024*512 elems).
__global__ __launch_bounds__(256) void cvt_all_kernel(CvtArgs a, float* __restrict__ out,
                                                      int total, int nb1,
                                                      __hip_bfloat16* __restrict__ w5bf,
                                                      const int* __restrict__ flag) {
  if ((int)blockIdx.x < nb1) {
    int t = blockIdx.x * 256 + threadIdx.x;
    if (t >= total) return;
    int s = 0;
    while (t >= a.off[s + 1]) s++;
    int j = t - a.off[s];
    float v;
    if (flag[0]) v = b2f(((const __hip_bfloat16*)a.src[s])[j]);
    else         v = ((const float*)a.src[s])[j];
    out[t] = v;
  } else {
    int t = (blockIdx.x - nb1) * 256 + threadIdx.x;   // 1024*512
    if (flag[0]) w5bf[t] = ((const __hip_bfloat16*)a.src[15])[t];
    else         w5bf[t] = __float2bfloat16(((const float*)a.src[15])[t]);
  }
}

// xx[b,m] = sum_c x[b,c,m]^2  (layer-1 raw input only)
template <int C>
__global__ __launch_bounds__(256) void xx_kernel(const float* __restrict__ x, long bstride,
                                                 float* __restrict__ xx) {
  int t = blockIdx.x * 256 + threadIdx.x;
  int b = t / NPTS, m = t % NPTS;
  const float* xb = x + (long)b * bstride + m;
  float s = 0.f;
#pragma unroll
  for (int c = 0; c < C; ++c) { float v = xb[(long)c * NPTS]; s = fmaf(v, v, s); }
  xx[t] = s;
}

// symmetric pd-GEMM (r12 version): 64x64 tile, triangular grid, LDS Ts mirror
template <int C>
__global__ __launch_bounds__(256) void pdgemmsym_kernel(const float* __restrict__ x, long bstride,
                                                        const float* __restrict__ xx,
                                                        unsigned* __restrict__ keys) {
  constexpr int KT = (C < 16) ? C : 16;
  __shared__ __align__(16) float At[KT][64];
  __shared__ __align__(16) float Bt[KT][64];
  __shared__ __align__(16) unsigned Ts[64][68];
  int t = blockIdx.x;
  int tj = (int)((sqrtf(8.f * (float)t + 1.f) - 1.f) * 0.5f);
  while ((tj + 1) * (tj + 2) / 2 <= t) tj++;
  while (tj * (tj + 1) / 2 > t) tj--;
  int ti = t - tj * (tj + 1) / 2;            // ti <= tj
  int n0 = ti * 64, m0 = tj * 64;
  int tid = threadIdx.x, tx = tid & 15, ty = tid >> 4;
  const float* xb = x + (long)blockIdx.y * bstride;
  float acc[4][4] = {};
  for (int k0 = 0; k0 < C; k0 += KT) {
    for (int lin = tid; lin < KT * 64; lin += 256) {
      int r = lin >> 6, col = lin & 63;
      At[r][col] = xb[(long)(k0 + r) * NPTS + n0 + col];
      Bt[r][col] = xb[(long)(k0 + r) * NPTS + m0 + col];
    }
    __syncthreads();
#pragma unroll
    for (int kc = 0; kc < KT; ++kc) {
      float4 av = *(const float4*)&At[kc][ty * 4];
      float4 bv = *(const float4*)&Bt[kc][tx * 4];
      acc[0][0] = fmaf(av.x, bv.x, acc[0][0]); acc[0][1] = fmaf(av.x, bv.y, acc[0][1]);
      acc[0][2] = fmaf(av.x, bv.z, acc[0][2]); acc[0][3] = fmaf(av.x, bv.w, acc[0][3]);
      acc[1][0] = fmaf(av.y, bv.x, acc[1][0]); acc[1][1] = fmaf(av.y, bv.y, acc[1][1]);
      acc[1][2] = fmaf(av.y, bv.z, acc[1][2]); acc[1][3] = fmaf(av.y, bv.w, acc[1][3]);
      acc[2][0] = fmaf(av.z, bv.x, acc[2][0]); acc[2][1] = fmaf(av.z, bv.y, acc[2][1]);
      acc[2][2] = fmaf(av.z, bv.z, acc[2][2]); acc[2][3] = fmaf(av.z, bv.w, acc[2][3]);
      acc[3][0] = fmaf(av.w, bv.x, acc[3][0]); acc[3][1] = fmaf(av.w, bv.y, acc[3][1]);
      acc[3][2] = fmaf(av.w, bv.z, acc[3][2]); acc[3][3] = fmaf(av.w, bv.w, acc[3][3]);
    }
    __syncthreads();
  }
  const float* xxq = xx + (long)blockIdx.y * NPTS;
  float4 xxm = *(const float4*)&xxq[m0 + tx * 4];
  unsigned* kb = keys + ((long)blockIdx.y << 22);
  unsigned ok[4][4];
#pragma unroll
  for (int i = 0; i < 4; ++i) {
    float xxn = xxq[n0 + ty * 4 + i];
    ok[i][0] = ordkey((-xxn - (-2.f * acc[i][0])) - xxm.x);
    ok[i][1] = ordkey((-xxn - (-2.f * acc[i][1])) - xxm.y);
    ok[i][2] = ordkey((-xxn - (-2.f * acc[i][2])) - xxm.z);
    ok[i][3] = ordkey((-xxn - (-2.f * acc[i][3])) - xxm.w);
    uint4 o = make_uint4(ok[i][0], ok[i][1], ok[i][2], ok[i][3]);
    *(uint4*)&kb[(long)(n0 + ty * 4 + i) * NPTS + m0 + tx * 4] = o;
  }
  if (ti != tj) {
#pragma unroll
    for (int i = 0; i < 4; ++i)
#pragma unroll
      for (int j = 0; j < 4; ++j) Ts[tx * 4 + j][ty * 4 + i] = ok[i][j];
    __syncthreads();
#pragma unroll
    for (int i = 0; i < 4; ++i)
      *(uint4*)&kb[(long)(m0 + ty * 4 + i) * NPTS + n0 + tx * 4] =
          *(const uint4*)&Ts[ty * 4 + i][tx * 4];
  }
}

// ---- select body: top-32 SET select (per-lane top-4 + ballot radix + verify) ----
static __device__ __forceinline__ void select_body(const unsigned* __restrict__ keys,
                                                   int* __restrict__ idxout, int q) {
  int lane = threadIdx.x & 63;
  int bloc = q >> 11, n = q & 2047;
  const uint4* rp = (const uint4*)(keys + ((long)((bloc << 11) | n) << 11));
  unsigned K[32];
#pragma unroll
  for (int t = 0; t < 8; ++t) {
    uint4 kk = rp[t * 64 + lane];
    K[4 * t + 0] = kk.x; K[4 * t + 1] = kk.y; K[4 * t + 2] = kk.z; K[4 * t + 3] = kk.w;
  }
  unsigned t0 = 0, t1 = 0, t2 = 0, t3 = 0;
#pragma unroll
  for (int s = 0; s < 32; ++s) {
    unsigned k = K[s];
    if (k > t3) {
      if (k > t1) {
        if (k > t0) { t3 = t2; t2 = t1; t1 = t0; t0 = k; }
        else        { t3 = t2; t2 = t1; t1 = k; }
      } else {
        if (k > t2) { t3 = t2; t2 = k; }
        else        { t3 = k; }
      }
    }
  }
  unsigned orv = t0 | t1 | t2 | t3, andv = t0 & t1 & t2 & t3;
#pragma unroll
  for (int xm = 32; xm >= 1; xm >>= 1) {
    orv  |= __shfl_xor(orv, xm);
    andv &= __shfl_xor(andv, xm);
  }
  unsigned V = orv ^ andv;
  unsigned P = andv & ~V;
  int need = KNN;
  for (int b = 31; b >= 0; --b) {
    unsigned bit = 1u << b;
    if (!(V & bit)) continue;
    unsigned hm = 0xFFFFFFFFu << b;
    unsigned Pb = (P & hm) | bit;
    int c = (int)__popcll(__ballot((t0 & hm) == Pb)) +
            (int)__popcll(__ballot((t1 & hm) == Pb)) +
            (int)__popcll(__ballot((t2 & hm) == Pb)) +
            (int)__popcll(__ballot((t3 & hm) == Pb));
    if (c >= need) P |= bit;
    else need -= c;
  }
  int cg = 0;
#pragma unroll
  for (int s = 0; s < 32; ++s) cg += (int)__popcll(__ballot(K[s] > P));
  if (cg > KNN - 1) {
    unsigned orf = K[0], anf = K[0];
#pragma unroll
    for (int s = 1; s < 32; ++s) { orf |= K[s]; anf &= K[s]; }
#pragma unroll
    for (int xm = 32; xm >= 1; xm >>= 1) {
      orf |= __shfl_xor(orf, xm);
      anf &= __shfl_xor(anf, xm);
    }
    unsigned Vf = orf ^ anf;
    P = anf & ~Vf;
    need = KNN;
    for (int b = 31; b >= 0; --b) {
      unsigned bit = 1u << b;
      if (!(Vf & bit)) continue;
      unsigned hm = 0xFFFFFFFFu << b;
      unsigned Pb = (P & hm) | bit;
      int c = 0;
#pragma unroll
      for (int s = 0; s < 32; ++s) c += (int)__popcll(__ballot((K[s] & hm) == Pb));
      if (c >= need) P |= bit;
      else need -= c;
    }
  }
  int* orow = idxout + ((bloc << 11) | n) * KNN;
  int base = 0;
  unsigned eqmask = 0;
#pragma unroll
  for (int s = 0; s < 32; ++s) {
    bool take = K[s] > P;
    unsigned long long bal = __ballot(take);
    if (take) {
      int pos = base + (int)__popcll(bal & ((1ull << lane) - 1ull));
      orow[pos] = ((s >> 2) << 8) + lane * 4 + (s & 3);
    }
    base += (int)__popcll(bal);
    if (K[s] == P) eqmask |= (1u << s);
  }
  int rem = KNN - base;
  for (int it = 0; it < rem; ++it) {
    unsigned mym = 0xFFFFFFFFu;
    if (eqmask) {
      int s = __ffs(eqmask) - 1;
      mym = (unsigned)(((s >> 2) << 8) + lane * 4 + (s & 3));
    }
    unsigned wm = mym;
#pragma unroll
    for (int xm = 32; xm >= 1; xm >>= 1) {
      unsigned o = __shfl_xor(wm, xm);
      wm = o < wm ? o : wm;
    }
    if (mym == wm) {
      orow[base + it] = (int)wm;
      eqmask &= eqmask - 1;
    }
  }
}

// ---- yzt body: point-major GEMM, yt[b][m][o], zt[b][m][o] ----
template <int C>
static __device__ __forceinline__ void yzt_body(const float* __restrict__ x, long bstride,
                                                const float* __restrict__ W, int O,
                                                float* __restrict__ yt, float* __restrict__ zt,
                                                int b, int m0, int o0) {
  constexpr int KT = (C < 16) ? C : 16;
  __shared__ __align__(16) float Xs[KT][64];
  __shared__ __align__(16) float Wy[KT][64];
  __shared__ __align__(16) float Wp[KT][64];
  int tid = threadIdx.x, tx = tid & 15, ty = tid >> 4;
  const float* xb = x + (long)b * bstride;
  const int twoC = 2 * C;
  float accy[4][4] = {}, accp[4][4] = {};
  for (int k0 = 0; k0 < C; k0 += KT) {
    for (int lin = tid; lin < KT * 64; lin += 256) {
      int r = lin >> 6, col = lin & 63;
      Xs[r][col] = xb[(long)(k0 + r) * NPTS + m0 + col];
      float wy = W[(o0 + col) * twoC + k0 + r];
      Wy[r][col] = wy;
      Wp[r][col] = W[(o0 + col) * twoC + C + k0 + r] - wy;
    }
    __syncthreads();
#pragma unroll
    for (int kc = 0; kc < KT; ++kc) {
      float4 wv = *(const float4*)&Wy[kc][tx * 4];
      float4 pv = *(const float4*)&Wp[kc][tx * 4];
      float xm[4];
      xm[0] = Xs[kc][ty * 4 + 0]; xm[1] = Xs[kc][ty * 4 + 1];
      xm[2] = Xs[kc][ty * 4 + 2]; xm[3] = Xs[kc][ty * 4 + 3];
#pragma unroll
      for (int i = 0; i < 4; ++i) {
        accy[i][0] = fmaf(xm[i], wv.x, accy[i][0]);
        accy[i][1] = fmaf(xm[i], wv.y, accy[i][1]);
        accy[i][2] = fmaf(xm[i], wv.z, accy[i][2]);
        accy[i][3] = fmaf(xm[i], wv.w, accy[i][3]);
        accp[i][0] = fmaf(xm[i], pv.x, accp[i][0]);
        accp[i][1] = fmaf(xm[i], pv.y, accp[i][1]);
        accp[i][2] = fmaf(xm[i], pv.z, accp[i][2]);
        accp[i][3] = fmaf(xm[i], pv.w, accp[i][3]);
      }
    }
    __syncthreads();
  }
#pragma unroll
  for (int i = 0; i < 4; ++i) {
    long base = ((long)b * NPTS + m0 + ty * 4 + i) * O + o0 + tx * 4;
    *(float4*)&yt[base] = make_float4(accy[i][0], accy[i][1], accy[i][2], accy[i][3]);
    *(float4*)&zt[base] = make_float4(accp[i][0], accp[i][1], accp[i][2], accp[i][3]);
  }
}

// fused: blocks [0,nsel) -> select; blocks [nsel, nsel+O64*32*NB) -> yzt
template <int C, int O64>
__global__ __launch_bounds__(256) void selyzt_kernel(const unsigned* __restrict__ keys,
                                                     int* __restrict__ idxout,
                                                     const float* __restrict__ x, long bstride,
                                                     const float* __restrict__ W,
                                                     float* __restrict__ yt,
                                                     float* __restrict__ zt, int nsel) {
  if ((int)blockIdx.x < nsel) {
    int wave = threadIdx.x >> 6;
    select_body(keys, idxout, blockIdx.x * 4 + wave);
  } else {
    int bid = blockIdx.x - nsel;           // o64 * (32*NB) + my*NB + b
    int b = bid % NB; bid /= NB;
    int m0 = (bid % 32) * 64; bid /= 32;
    int o0 = bid * 64;
    yzt_body<C>(x, bstride, W, O64 * 64, yt, zt, b, m0, o0);
  }
}

// standalone fallbacks (bpass < NB path)
__global__ __launch_bounds__(256) void select_kernel(const unsigned* __restrict__ keys,
                                                     int* __restrict__ idxout) {
  int wave = threadIdx.x >> 6;
  select_body(keys, idxout, blockIdx.x * 4 + wave);
}

template <int C>
__global__ __launch_bounds__(256) void yzt_kernel(const float* __restrict__ x, long bstride,
                                                  const float* __restrict__ W, int O,
                                                  float* __restrict__ yt, float* __restrict__ zt) {
  yzt_body<C>(x, bstride, W, O, yt, zt, blockIdx.z, blockIdx.y * 64, blockIdx.x * 64);
}

// gmaxt: one wave per query n; emits xx for next layer + bf16 point-major cat copy
template <int RO>
__global__ __launch_bounds__(256) void gmaxt_kernel(const float* __restrict__ yt,
                                                    const float* __restrict__ zt,
                                                    const int* __restrict__ idx,
                                                    const float* __restrict__ g,
                                                    const float* __restrict__ bb,
                                                    float* __restrict__ out, long obstride,
                                                    float* __restrict__ xxout,
                                                    __hip_bfloat16* __restrict__ catbf, int loff) {
  constexpr int O = RO * 64;
  int wave = threadIdx.x >> 6, lane = threadIdx.x & 63;
  int n = blockIdx.x * 4 + wave, b = blockIdx.y;
  int jreg = idx[((b << 11) + n) * KNN + (lane & 31)];
  int obase = lane * RO;
  float gs[RO], bs[RO], zr[RO], acc[RO];
  loadv(zt + ((long)(b << 11) + n) * O + obase, zr);
#pragma unroll
  for (int r = 0; r < RO; ++r) {
    gs[r] = g[obase + r] * ISQ;
    bs[r] = bb[obase + r];
    acc[r] = -INFINITY;
  }
  const float* yb = yt + ((long)(b << 11)) * O + obase;
#pragma unroll
  for (int k = 0; k < KNN; ++k) {
    int j = __shfl(jreg, k);
    float yv[RO];
    loadv(yb + (long)j * O, yv);
#pragma unroll
    for (int r = 0; r < RO; ++r) {
      float v = fmaf(gs[r], yv[r] + zr[r], bs[r]);
      v = v >= 0.f ? v : 0.2f * v;
      acc[r] = fmaxf(acc[r], v);
    }
  }
  float* op = out + (long)b * obstride + (long)obase * NPTS + n;
#pragma unroll
  for (int r = 0; r < RO; ++r) op[(long)r * NPTS] = acc[r];
  __hip_bfloat16* cb = catbf + ((long)(b << 11) + n) * 512 + loff + obase;
#pragma unroll
  for (int r = 0; r < RO; ++r) cb[r] = __float2bfloat16(acc[r]);
  if (xxout) {
    float ss = 0.f;
#pragma unroll
    for (int r = 0; r < RO; ++r) ss = fmaf(acc[r], acc[r], ss);
    ss = wave_red_sum(ss);
    if (lane == 0) xxout[(b << 11) + n] = ss;
  }
}

// MFMA W5 GEMM + BN + leaky + 64n partial max. LDS-staged B, double-buffered.
__global__ __launch_bounds__(256) void gemm5m_kernel(const __hip_bfloat16* __restrict__ catbf,
                                                     const __hip_bfloat16* __restrict__ w5bf,
                                                     const float* __restrict__ g5,
                                                     const float* __restrict__ b5,
                                                     float* __restrict__ pmax) {
  __shared__ __align__(16) short Bs[2][8 * 64 * 8];
  int b = blockIdx.z, po0 = blockIdx.y * 128, n0 = blockIdx.x * 64;
  int wave = threadIdx.x >> 6, lane = threadIdx.x & 63;
  int quad = lane >> 4, l15 = lane & 15;
  const short* cbase = (const short*)catbf + ((long)(b << 11) + n0) * 512;
  const short* abase0 = (const short*)w5bf + (long)(po0 + wave * 32 + l15) * 512 + quad * 8;
  const short* abase1 = abase0 + 16 * 512;
  const short* bsrc0 = cbase + (long)lane * 512 + (2 * wave + 0) * 8;
  const short* bsrc1 = cbase + (long)lane * 512 + (2 * wave + 1) * 8;
  short* bdst0 = &Bs[0][((2 * wave + 0) * 64 + lane) * 8];
  short* bdst1 = &Bs[0][((2 * wave + 1) * 64 + lane) * 8];
  const int bufstride = 8 * 64 * 8;

  short8v Br[2][2], Ar[2][2][2];
  f32x4 acc[2][4] = {};

  Br[0][0] = *(const short8v*)(bsrc0);
  Br[0][1] = *(const short8v*)(bsrc1);
#pragma unroll
  for (int h = 0; h < 2; ++h)
#pragma unroll
    for (int j = 0; j < 2; ++j)
      Ar[0][h][j] = *(const short8v*)((h ? abase1 : abase0) + j * 32);
  *(short8v*)bdst0 = Br[0][0];
  *(short8v*)bdst1 = Br[0][1];
  Br[1][0] = *(const short8v*)(bsrc0 + 64);
  Br[1][1] = *(const short8v*)(bsrc1 + 64);
#pragma unroll
  for (int h = 0; h < 2; ++h)
#pragma unroll
    for (int j = 0; j < 2; ++j)
      Ar[1][h][j] = *(const short8v*)((h ? abase1 : abase0) + 64 + j * 32);
  __syncthreads();

  for (int it = 0; it < 8; ++it) {
    int cur = it & 1;
    const short* lb = &Bs[cur][0];
#pragma unroll
    for (int j = 0; j < 2; ++j) {
#pragma unroll
      for (int nt = 0; nt < 4; ++nt) {
        short8v bf = *(const short8v*)(lb + ((j * 4 + quad) * 64 + nt * 16 + l15) * 8);
        acc[0][nt] = __builtin_amdgcn_mfma_f32_16x16x32_bf16(Ar[cur][0][j], bf, acc[0][nt], 0, 0, 0);
        acc[1][nt] = __builtin_amdgcn_mfma_f32_16x16x32_bf16(Ar[cur][1][j], bf, acc[1][nt], 0, 0, 0);
      }
    }
    if (it < 7) {
      if (it < 6) {
        int ks = (it + 2) * 64;
        Br[cur][0] = *(const short8v*)(bsrc0 + ks);
        Br[cur][1] = *(const short8v*)(bsrc1 + ks);
#pragma unroll
        for (int h = 0; h < 2; ++h)
#pragma unroll
          for (int j = 0; j < 2; ++j)
            Ar[cur][h][j] = *(const short8v*)((h ? abase1 : abase0) + ks + j * 32);
      }
      int nb = cur ^ 1;
      *(short8v*)(bdst0 + nb * bufstride) = Br[nb][0];
      *(short8v*)(bdst1 + nb * bufstride) = Br[nb][1];
      __syncthreads();
    }
  }

#pragma unroll
  for (int h = 0; h < 2; ++h) {
#pragma unroll
    for (int r = 0; r < 4; ++r) {
      int po = po0 + wave * 32 + h * 16 + quad * 4 + r;
      float sc = g5[po] * ISQ;
      float bi = b5[po];
      float mx = -INFINITY;
#pragma unroll
      for (int nt = 0; nt < 4; ++nt) {
        float v = fmaf(sc, acc[h][nt][r], bi);
        v = v >= 0.f ? v : 0.2f * v;
        mx = fmaxf(mx, v);
      }
#pragma unroll
      for (int xm = 1; xm < 16; xm <<= 1) mx = fmaxf(mx, __shfl_xor(mx, xm));
      if (l15 == 0) pmax[(long)(b * 1024 + po) * 32 + blockIdx.x] = mx;
    }
  }
}

// merged: blocks 0..15 -> global-max reduce of pmax into v; blocks 16..17 -> lf/nf
__global__ __launch_bounds__(256) void redlfnf_kernel(const float* __restrict__ pmax,
                                                      const float* __restrict__ l,
                                                      const float* __restrict__ nn,
                                                      const float* __restrict__ W6,
                                                      const float* __restrict__ g6,
                                                      const float* __restrict__ b6,
                                                      const float* __restrict__ W7,
                                                      const float* __restrict__ g7,
                                                      const float* __restrict__ b7,
                                                      float* __restrict__ v) {
  if (blockIdx.x < 16) {
    int t = blockIdx.x * 256 + threadIdx.x;   // b*1024 + po  (4096)
    float mx = -INFINITY;
#pragma unroll
    for (int j = 0; j < 32; ++j) mx = fmaxf(mx, pmax[(long)t * 32 + j]);
    int b = t >> 10, po = t & 1023;
    v[b * 1152 + po] = mx;
  } else {
    int idx = (blockIdx.x - 16) * 256 + threadIdx.x;  // 512 work items
    int b = idx >> 7, t = idx & 127;
    if (t < 64) {
      float s = 0.f;
#pragma unroll
      for (int c = 0; c < 5; ++c) s = fmaf(W6[t * 5 + c], l[b * 5 + c], s);
      float val = fmaf(g6[t] * ISQ, s, b6[t]);
      v[b * 1152 + 1024 + t] = val >= 0.f ? val : 0.2f * val;
    } else {
      int o = t - 64;
      float s = 0.f;
#pragma unroll
      for (int c = 0; c < 7; ++c) s = fmaf(W7[o * 7 + c], nn[b * 7 + c], s);
      float val = fmaf(g7[o] * ISQ, s, b7[o]);
      v[b * 1152 + 1088 + o] = val >= 0.f ? val : 0.2f * val;
    }
  }
}

// one wave per output row; lane-strided dot + shuffle reduce
__global__ __launch_bounds__(256) void head1_kernel(const float* __restrict__ v,
                                                    const float* __restrict__ L1,
                                                    const float* __restrict__ g8,
                                                    const float* __restrict__ b8,
                                                    float* __restrict__ v1) {
  int wave = threadIdx.x >> 6, lane = threadIdx.x & 63;
  int t = blockIdx.x * 4 + wave;   // b*512 + o  (2048)
  int b = t >> 9, o = t & 511;
  const float* vb = v + b * 1152;
  const float* wr = L1 + (long)o * 1152;
  float s = 0.f;
#pragma unroll
  for (int c = lane; c < 1152; c += 64) s = fmaf(wr[c], vb[c], s);
  s = wave_red_sum(s);
  if (lane == 0) {
    float val = fmaf(g8[o] * ISQ, s, b8[o]);
    v1[t] = fmaxf(val, 0.f);
  }
}

__global__ __launch_bounds__(256) void head2_kernel(const float* __restrict__ v1,
                                                    const float* __restrict__ L2,
                                                    const float* __restrict__ L2b,
                                                    const float* __restrict__ g9,
                                                    const float* __restrict__ b9,
                                                    float* __restrict__ v2) {
  int wave = threadIdx.x >> 6, lane = threadIdx.x & 63;
  int t = blockIdx.x * 4 + wave;   // b*256 + o  (1024)
  int b = t >> 8, o = t & 255;
  const float* vb = v1 + b * 512;
  const float* wr = L2 + (long)o * 512;
  float s = 0.f;
#pragma unroll
  for (int c = lane; c < 512; c += 64) s = fmaf(wr[c], vb[c], s);
  s = wave_red_sum(s);
  if (lane == 0) {
    float sv = s + L2b[o];
    float val = fmaf(g9[o] * ISQ, sv, b9[o]);
    v2[t] = fmaxf(val, 0.f);
  }
}

__global__ __launch_bounds__(256) void head3_kernel(const float* __restrict__ v2,
                                                    const float* __restrict__ L3,
                                                    const float* __restrict__ L3b,
                                                    void* __restrict__ out,
                                                    const int* __restrict__ flag) {
  int wave = threadIdx.x >> 6, lane = threadIdx.x & 63;
  int t = blockIdx.x * 4 + wave;   // b*28 + o  (112)
  if (t >= 112) return;
  int b = t / 28, o = t % 28;
  const float* vb = v2 + b * 256;
  const float* wr = L3 + o * 256;
  float s = 0.f;
#pragma unroll
  for (int c = lane; c < 256; c += 64) s = fmaf(wr[c], vb[c], s);
  s = wave_red_sum(s);
  if (lane == 0) {
    float sv = s + L3b[o];
    if (flag[0]) ((__hip_bfloat16*)out)[t] = __float2bfloat16(sv);
    else         ((float*)out)[t] = sv;
  }
}

extern "C" void kernel_launch(void* const* d_in, const int* in_sizes, int n_in,
                              void* d_out, int out_size, void* d_ws, size_t ws_size,
                              hipStream_t stream) {
  CvtArgs ca;
  int off[NIN + 1];
  off[0] = 0;
  for (int i = 0; i < NIN; ++i) {
    ca.src[i] = d_in[i];
    off[i + 1] = off[i] + in_sizes[i];
    ca.off[i] = off[i];
  }
  ca.off[NIN] = off[NIN];
  const int total = off[NIN];

  int* flag = (int*)d_ws;
  float* fin = (float*)((char*)d_ws + 64);
  const float* xf  = fin + off[0];
  const float* lf  = fin + off[1];
  const float* nf  = fin + off[2];
  const float* W1f = fin + off[3];  const float* g1f = fin + off[4];  const float* b1f = fin + off[5];
  const float* W2f = fin + off[6];  const float* g2f = fin + off[7];  const float* b2f_ = fin + off[8];
  const float* W3f = fin + off[9];  const float* g3f = fin + off[10]; const float* b3f = fin + off[11];
  const float* W4f = fin + off[12]; const float* g4f = fin + off[13]; const float* b4f = fin + off[14];
  const float* g5f = fin + off[16]; const float* b5f = fin + off[17];
  const float* W6f = fin + off[18]; const float* g6f = fin + off[19]; const float* b6f = fin + off[20];
  const float* W7f = fin + off[21]; const float* g7f = fin + off[22]; const float* b7f = fin + off[23];
  const float* L1f = fin + off[24]; const float* g8f = fin + off[25]; const float* b8f = fin + off[26];
  const float* L2f = fin + off[27]; const float* L2bf = fin + off[28];
  const float* g9f = fin + off[29]; const float* b9f = fin + off[30];
  const float* L3f = fin + off[31]; const float* L3bf = fin + off[32];

  float* p = fin + ((total + 15) & ~15);
  float* cat  = p;                               // 4*512*2048 (fp32, channel-major)
  float* yb   = cat + 4 * 512 * NPTS;            // 4*2048*256 (point-major)
  float* zb   = yb + 4 * 256 * NPTS;             // 4*2048*256 (point-major)
  float* xxb  = zb + 4 * 256 * NPTS;             // 4*2048
  int*   idxb = (int*)(xxb + 4 * NPTS);          // 4*2048*32
  float* pmax = (float*)(idxb + 4 * NPTS * KNN); // 4*1024*32
  float* vb   = pmax + 4 * 1024 * 32;            // 4*1152
  float* v1b  = vb + 4 * 1152;                   // 4*512
  float* v2b  = v1b + 4 * 512;                   // 4*256
  __hip_bfloat16* w5bf  = (__hip_bfloat16*)(v2b + 4 * 256);           // 1024*512 bf16
  __hip_bfloat16* catbf = w5bf + 1024 * 512;                          // 4*2048*512 bf16
  unsigned* keys_tail = (unsigned*)(catbf + (size_t)4 * NPTS * 512);

  size_t need_full = (size_t)((char*)(keys_tail + (size_t)NB * NPTS * NPTS) - (char*)d_ws);
  int bpass = (ws_size >= need_full) ? NB : 1;
  unsigned* keys = (bpass == NB) ? keys_tail : (unsigned*)yb;

  const long bst1 = 3L * NPTS;
  const long bstc = 512L * NPTS;
  const int NTRI = 32 * 33 / 2;   // 528 triangular 64x64 tiles
  const int nb1 = (total + 255) / 256;
  const int NSEL = NB * 512;      // 2048 select blocks (4 rows each)

  detect_kernel<<<1, 64, 0, stream>>>((const unsigned short*)d_in[0], flag);
  cvt_all_kernel<<<nb1 + 2048, 256, 0, stream>>>(ca, fin, total, nb1, w5bf, flag);

  // ---- layer 1: C=3, O=64
  xx_kernel<3><<<32, 256, 0, stream>>>(xf, bst1, xxb);
  if (bpass == NB) {
    pdgemmsym_kernel<3><<<dim3(NTRI, NB), 256, 0, stream>>>(xf, bst1, xxb, keys);
    selyzt_kernel<3, 1><<<NSEL + 1 * 32 * NB, 256, 0, stream>>>(keys, idxb, xf, bst1, W1f, yb, zb, NSEL);
  } else {
    for (int b0 = 0; b0 < NB; b0 += bpass) {
      pdgemmsym_kernel<3><<<dim3(NTRI, bpass), 256, 0, stream>>>(xf + b0 * bst1, bst1, xxb + b0 * NPTS, keys);
      select_kernel<<<512 * bpass, 256, 0, stream>>>(keys, idxb + (long)b0 * NPTS * KNN);
    }
    yzt_kernel<3><<<dim3(1, 32, NB), 256, 0, stream>>>(xf, bst1, W1f, 64, yb, zb);
  }
  gmaxt_kernel<1><<<dim3(512, NB), 256, 0, stream>>>(yb, zb, idxb, g1f, b1f, cat, bstc, xxb, catbf, 0);

  // ---- layer 2: C=64, O=64
  if (bpass == NB) {
    pdgemmsym_kernel<64><<<dim3(NTRI, NB), 256, 0, stream>>>(cat, bstc, xxb, keys);
    selyzt_kernel<64, 1><<<NSEL + 1 * 32 * NB, 256, 0, stream>>>(keys, idxb, cat, bstc, W2f, yb, zb, NSEL);
  } else {
    for (int b0 = 0; b0 < NB; b0 += bpass) {
      pdgemmsym_kernel<64><<<dim3(NTRI, bpass), 256, 0, stream>>>(cat + b0 * bstc, bstc, xxb + b0 * NPTS, keys);
      select_kernel<<<512 * bpass, 256, 0, stream>>>(keys, idxb + (long)b0 * NPTS * KNN);
    }
    yzt_kernel<64><<<dim3(1, 32, NB), 256, 0, stream>>>(cat, bstc, W2f, 64, yb, zb);
  }
  gmaxt_kernel<1><<<dim3(512, NB), 256, 0, stream>>>(yb, zb, idxb, g2f, b2f_, cat + 64L * NPTS, bstc, xxb, catbf, 64);

  // ---- layer 3: C=64, O=128
  if (bpass == NB) {
    pdgemmsym_kernel<64><<<dim3(NTRI, NB), 256, 0, stream>>>(cat + 64L * NPTS, bstc, xxb, keys);
    selyzt_kernel<64, 2><<<NSEL + 2 * 32 * NB, 256, 0, stream>>>(keys, idxb, cat + 64L * NPTS, bstc, W3f, yb, zb, NSEL);
  } else {
    for (int b0 = 0; b0 < NB; b0 += bpass) {
      pdgemmsym_kernel<64><<<dim3(NTRI, bpass), 256, 0, stream>>>(cat + 64L * NPTS + b0 * bstc, bstc, xxb + b0 * NPTS, keys);
      select_kernel<<<512 * bpass, 256, 0, stream>>>(keys, idxb + (long)b0 * NPTS * KNN);
    }
    yzt_kernel<64><<<dim3(2, 32, NB), 256, 0, stream>>>(cat + 64L * NPTS, bstc, W3f, 128, yb, zb);
  }
  gmaxt_kernel<2><<<dim3(512, NB), 256, 0, stream>>>(yb, zb, idxb, g3f, b3f, cat + 128L * NPTS, bstc, xxb, catbf, 128);

  // ---- layer 4: C=128, O=256
  if (bpass == NB) {
    pdgemmsym_kernel<128><<<dim3(NTRI, NB), 256, 0, stream>>>(cat + 128L * NPTS, bstc, xxb, keys);
    selyzt_kernel<128, 4><<<NSEL + 4 * 32 * NB, 256, 0, stream>>>(keys, idxb, cat + 128L * NPTS, bstc, W4f, yb, zb, NSEL);
  } else {
    for (int b0 = 0; b0 < NB; b0 += bpass) {
      pdgemmsym_kernel<128><<<dim3(NTRI, bpass), 256, 0, stream>>>(cat + 128L * NPTS + b0 * bstc, bstc, xxb + b0 * NPTS, keys);
      select_kernel<<<512 * bpass, 256, 0, stream>>>(keys, idxb + (long)b0 * NPTS * KNN);
    }
    yzt_kernel<128><<<dim3(4, 32, NB), 256, 0, stream>>>(cat + 128L * NPTS, bstc, W4f, 256, yb, zb);
  }
  gmaxt_kernel<4><<<dim3(512, NB), 256, 0, stream>>>(yb, zb, idxb, g4f, b4f, cat + 256L * NPTS, bstc, (float*)nullptr, catbf, 256);

  // ---- conv5 (bf16 MFMA, LDS-staged B, double-buffered) + BN + leaky + global max
  gemm5m_kernel<<<dim3(32, 8, NB), 256, 0, stream>>>(catbf, w5bf, g5f, b5f, pmax);
  redlfnf_kernel<<<18, 256, 0, stream>>>(pmax, lf, nf, W6f, g6f, b6f, W7f, g7f, b7f, vb);

  head1_kernel<<<512, 256, 0, stream>>>(vb, L1f, g8f, b8f, v1b);
  head2_kernel<<<256, 256, 0, stream>>>(v1b, L2f, L2bf, g9f, b9f, v2b);
  head3_kernel<<<28, 256, 0, stream>>>(v2b, L3f, L3bf, d_out, flag);
}